// Round 1
// baseline (149.132 us; speedup 1.0000x reference)
//
#include <hip/hip_runtime.h>
#include <math.h>

// ---------------------------------------------------------------------------
// NormalDistributionChecker1D: soft chi-square normality test on 16.7M floats.
// Pass 1: sum / sumsq reduction (HBM-bound).
// Pass 2: cum[k] = sum_i sigmoid(100*(zs_k - z_i)), k=0..8 (trans-bound).
// Pass 3: scalar epilogue (chi2, softmax interp) on 1 thread, fp64.
// Accumulation: fp32 per-thread -> fp64 wave/block reduce -> fixed-point
// (x 2^20) int64 atomics: deterministic, fast HW integer atomics.
// ---------------------------------------------------------------------------

#if __has_builtin(__builtin_amdgcn_exp2f)
#define EXP2F(x) __builtin_amdgcn_exp2f(x)
#else
#define EXP2F(x) exp2f(x)
#endif
#if __has_builtin(__builtin_amdgcn_rcpf)
#define RCPF(x) __builtin_amdgcn_rcpf(x)
#else
#define RCPF(x) (1.0f / (x))
#endif

#define FIXED_SCALE 1048576.0   // 2^20 fixed-point scale for atomics

static __device__ __forceinline__ double wave_reduce_d(double v) {
#pragma unroll
    for (int off = 32; off > 0; off >>= 1) v += __shfl_down(v, off);
    return v;
}

static __device__ __forceinline__ void atomic_add_fixed(long long* addr, double v) {
    long long q = (long long)llround(v * FIXED_SCALE);
    atomicAdd((unsigned long long*)addr, (unsigned long long)q);
}

// ws layout (long long): [0]=sum, [1]=sumsq, [2..10]=cum[0..8]
__global__ __launch_bounds__(256) void pass1_stats(const float* __restrict__ x,
                                                   long long* __restrict__ ws, int n) {
    const int tid = blockIdx.x * blockDim.x + threadIdx.x;
    const int stride = gridDim.x * blockDim.x;
    const int n4 = n >> 2;
    const float4* __restrict__ x4 = (const float4*)x;

    float fs = 0.f, fss = 0.f;
    for (int i = tid; i < n4; i += stride) {
        float4 v = x4[i];
        fs += v.x + v.y + v.z + v.w;
        fss = fmaf(v.x, v.x, fss);
        fss = fmaf(v.y, v.y, fss);
        fss = fmaf(v.z, v.z, fss);
        fss = fmaf(v.w, v.w, fss);
    }
    if (tid == 0) {  // scalar tail (n%4) — never taken for n=16.7M, kept for safety
        for (int i = n4 << 2; i < n; ++i) {
            float v = x[i];
            fs += v;
            fss = fmaf(v, v, fss);
        }
    }

    double s = wave_reduce_d((double)fs);
    double ss = wave_reduce_d((double)fss);

    __shared__ double sm[4][2];
    const int lane = threadIdx.x & 63, wid = threadIdx.x >> 6;
    if (lane == 0) { sm[wid][0] = s; sm[wid][1] = ss; }
    __syncthreads();
    if (threadIdx.x == 0) {
        double ts = 0, tss = 0;
#pragma unroll
        for (int w = 0; w < 4; ++w) { ts += sm[w][0]; tss += sm[w][1]; }
        atomic_add_fixed(&ws[0], ts);
        atomic_add_fixed(&ws[1], tss);
    }
}

__global__ __launch_bounds__(256) void pass2_cum(const float* __restrict__ x,
                                                 const long long* __restrict__ ws_stats,
                                                 long long* __restrict__ ws_cum, int n) {
    constexpr float ZS[9] = {-1.2815516f, -0.8416212f, -0.5244005f, -0.2533471f, 0.0f,
                             0.2533471f,  0.5244005f,  0.8416212f,  1.2815516f};
    const double Ld = 144.26950408889634;  // 100 * log2(e)

    const double nd = (double)n;
    const double s = (double)ws_stats[0] / FIXED_SCALE;
    const double ss = (double)ws_stats[1] / FIXED_SCALE;
    const double mean = s / nd;
    const double var = (ss - s * s / nd) / (nd - 1.0);  // Bessel (ddof=1)
    const double inv_std = 1.0 / sqrt(var);

    // a = L * z = L*inv_std*x - L*inv_std*mean ;  sig_k = 1/(1+exp2(a - C_k))
    const float S = (float)(Ld * inv_std);
    const float B = (float)(-Ld * inv_std * mean);
    float C[9];
#pragma unroll
    for (int k = 0; k < 9; ++k) C[k] = (float)(Ld * (double)ZS[k]);

    float acc[9];
#pragma unroll
    for (int k = 0; k < 9; ++k) acc[k] = 0.f;

    const int tid = blockIdx.x * blockDim.x + threadIdx.x;
    const int stride = gridDim.x * blockDim.x;
    const int n4 = n >> 2;
    const float4* __restrict__ x4 = (const float4*)x;

    for (int i = tid; i < n4; i += stride) {
        float4 v = x4[i];
        float a0 = fmaf(v.x, S, B);
        float a1 = fmaf(v.y, S, B);
        float a2 = fmaf(v.z, S, B);
        float a3 = fmaf(v.w, S, B);
#pragma unroll
        for (int k = 0; k < 9; ++k) {
            acc[k] += RCPF(1.0f + EXP2F(a0 - C[k]));
            acc[k] += RCPF(1.0f + EXP2F(a1 - C[k]));
            acc[k] += RCPF(1.0f + EXP2F(a2 - C[k]));
            acc[k] += RCPF(1.0f + EXP2F(a3 - C[k]));
        }
    }
    if (tid == 0) {  // scalar tail — never taken for n=16.7M
        for (int i = n4 << 2; i < n; ++i) {
            float a = fmaf(x[i], S, B);
#pragma unroll
            for (int k = 0; k < 9; ++k) acc[k] += RCPF(1.0f + EXP2F(a - C[k]));
        }
    }

    __shared__ double sm[4][9];
    const int lane = threadIdx.x & 63, wid = threadIdx.x >> 6;
#pragma unroll
    for (int k = 0; k < 9; ++k) {
        double r = wave_reduce_d((double)acc[k]);
        if (lane == 0) sm[wid][k] = r;
    }
    __syncthreads();
    if (threadIdx.x < 9) {
        const int k = threadIdx.x;
        double t = sm[0][k] + sm[1][k] + sm[2][k] + sm[3][k];
        atomic_add_fixed(&ws_cum[k], t);
    }
}

__global__ void finalize_kernel(const long long* __restrict__ ws, float* __restrict__ out,
                                int n) {
    const double CRIT[9] = {14.683657, 12.242145, 10.656372, 9.413640, 8.342832,
                            7.357034,  6.393306,  5.380053,  4.168159};
    const double nd = (double)n;
    double cum[9];
#pragma unroll
    for (int k = 0; k < 9; ++k) cum[k] = (double)ws[2 + k] / FIXED_SCALE;

    double actual[10];
    actual[0] = cum[0];
#pragma unroll
    for (int k = 1; k < 9; ++k) actual[k] = cum[k] - cum[k - 1];
    actual[9] = nd - cum[8];

    const double expected = nd * (double)0.1f;  // n * EXPECTED_PCT (fp32 0.1)
    const double denom = expected + 1e-7;
    double chi2 = 0.0;
#pragma unroll
    for (int j = 0; j < 10; ++j) {
        double d = actual[j] - expected;
        chi2 += d * d / denom;
    }

    // w = softmax(-|chi2 - CRIT|); p = 1 - sum(w * quantiles)
    double dneg[9], m = -1e300;
#pragma unroll
    for (int k = 0; k < 9; ++k) {
        dneg[k] = -fabs(chi2 - CRIT[k]);
        if (dneg[k] > m) m = dneg[k];
    }
    double W = 0.0, PQ = 0.0;
#pragma unroll
    for (int k = 0; k < 9; ++k) {
        double w = exp(dneg[k] - m);
        W += w;
        PQ += w * (0.1 * (double)(k + 1));
    }
    double p = 1.0 - PQ / W;
    double excess = (chi2 - 14.683657) / 100.0;
    if (excess < 0.0) excess = 0.0;
    out[0] = (float)(p + excess);
}

extern "C" void kernel_launch(void* const* d_in, const int* in_sizes, int n_in,
                              void* d_out, int out_size, void* d_ws, size_t ws_size,
                              hipStream_t stream) {
    const float* x = (const float*)d_in[0];
    const int n = in_sizes[0];
    long long* ws = (long long*)d_ws;

    // ws is re-poisoned to 0xAA before every timed call — zero the 11 slots.
    hipMemsetAsync(d_ws, 0, 16 * sizeof(long long), stream);

    const int threads = 256;
    const int blocks = 1024;  // 4 blocks/CU; 16 float4 iters/thread in pass1
    pass1_stats<<<blocks, threads, 0, stream>>>(x, ws, n);
    pass2_cum<<<blocks, threads, 0, stream>>>(x, ws, ws + 2, n);
    finalize_kernel<<<1, 1, 0, stream>>>(ws, (float*)d_out, n);
}